// Round 20
// baseline (46.663 us; speedup 1.0000x reference)
//
#include <hip/hip_runtime.h>
#include <math.h>

constexpr int NB = 16;    // batch
constexpr int SL = 1024;  // L
constexpr int ND = 128;   // D
constexpr int NH = 256;   // H
constexpr int NSTILE = 18; // s-tiles of 32 (576 slots)
constexpr int NKTILE = 17; // k-tiles of 32 (544 slots)
constexpr int EPAD = 584;  // LDS row stride for E tiles

// bf16 plane layout (ushort element indices)
// CS/DD: [b][dblk8][stile18][sg4][dw16][8]  (tile = 1024 elems)
// FR/FI: [b][dblk8][ktile17][kg4][dw16][8]
constexpr size_t PLANE_S = (size_t)NB * 8 * NSTILE * 1024;
constexpr size_t PLANE_K = (size_t)NB * 8 * NKTILE * 1024;
constexpr size_t CS_OFF = 0;
constexpr size_t DD_OFF = PLANE_S;
constexpr size_t FR_OFF = 2 * PLANE_S;
constexpr size_t FI_OFF = 2 * PLANE_S + PLANE_K;
// float scratch after bf16 region (float element indices)
constexpr size_t F32B      = PLANE_S + PLANE_K;
constexpr size_t P_OFF     = F32B;                // [2][16][16][128]
constexpr size_t SCALE_OFF = P_OFF + 2 * 16 * 16 * 128;
constexpr size_t BIAS_OFF  = SCALE_OFF + NB * ND;

typedef float          f32x4 __attribute__((ext_vector_type(4)));
typedef unsigned int   u32x4 __attribute__((ext_vector_type(4)));
typedef unsigned short u16x8 __attribute__((ext_vector_type(8)));

__device__ __forceinline__ unsigned short f2bf(float f) {
    unsigned u = __float_as_uint(f);
    return (unsigned short)((u + 0x7FFFu + ((u >> 16) & 1u)) >> 16);
}
__device__ __forceinline__ float hw_sin(float rev) {   // sin(2*pi*rev)
    float r; asm("v_sin_f32 %0, %1" : "=v"(r) : "v"(rev)); return r;
}
__device__ __forceinline__ float hw_cos(float rev) {   // cos(2*pi*rev)
    float r; asm("v_cos_f32 %0, %1" : "=v"(r) : "v"(rev)); return r;
}
__device__ __forceinline__ void mfma16(f32x4& acc, u32x4 a, u32x4 b) {
    asm("v_mfma_f32_16x16x32_bf16 %0, %1, %2, %0" : "+v"(acc) : "v"(a), "v"(b));
}
__device__ __forceinline__ float4 f4add(float4 a, float4 b) {
    return make_float4(a.x + b.x, a.y + b.y, a.z + b.z, a.w + b.w);
}

// ---------------- K1: fused front kernel (R19-identical) ----------------
__global__ __launch_bounds__(256) void k_front(const float* __restrict__ x,
                                               const float* __restrict__ y,
                                               const float* __restrict__ z,
                                               const int* __restrict__ len_x,
                                               float* __restrict__ wsf,
                                               unsigned short* __restrict__ wsb,
                                               float* __restrict__ out) {
    const int blk = blockIdx.x;
    const int tid = threadIdx.x;
    __shared__ float4 red4[256];

    if (blk < 512) {
        const int ch  = blk & 15;
        const int b   = (blk >> 4) & 15;
        const int src = blk >> 8;
        const float* base = (src == 0 ? y : z) + ((size_t)b * SL + ch * 64) * ND;
        const int dg = tid & 31;   // d-quad group
        const int tq = tid >> 5;   // 0..7
        float4 s = make_float4(0.f, 0.f, 0.f, 0.f);
#pragma unroll
        for (int j = 0; j < 8; ++j)
            s = f4add(s, *(const float4*)&base[(size_t)(tq + 8 * j) * ND + dg * 4]);
        red4[tid] = s;
        __syncthreads();
        if (tq < 4) red4[tid] = f4add(red4[tid], red4[tid + 128]);
        __syncthreads();
        if (tq < 2) red4[tid] = f4add(red4[tid], red4[tid + 64]);
        __syncthreads();
        if (tq == 0) {
            const float4 r = f4add(red4[dg], red4[dg + 32]);
            *(float4*)&wsf[P_OFF + ((size_t)((src * NB + b) * 16 + ch)) * ND + dg * 4] = r;
        }
        return;
    }

    if (blk < 800) {
        const int pb = blk - 512;
        const int bx = pb % NSTILE;   // stile
        const int b  = pb / NSTILE;
        const int l = len_x[b];
        const int NS = (l >> 1) + 1;
        const int d = tid & 127;
        const int slot = tid >> 7;
        const int dblk = d >> 4, dw = d & 15;
#pragma unroll
        for (int it = 0; it < 2; ++it) {
            const int sb = (bx * 4 + slot * 2 + it) * 8;   // octet start
            u16x8 cb, db;
#pragma unroll
            for (int j = 0; j < 8; ++j) {
                const int s = sb + j;
                float c = 0.f, dd = 0.f;
                if (s < NS) {
                    const float a = x[((size_t)b * SL + s) * ND + d];
                    float p = 0.f;
                    if (s > 0 && 2 * s != l) p = x[((size_t)b * SL + (l - s)) * ND + d];
                    c = a + p; dd = a - p;
                }
                cb[j] = f2bf(c); db[j] = f2bf(dd);
            }
            const int sg = (sb >> 3) & 3;
            const size_t ro = ((size_t)((b * 8 + dblk) * NSTILE) + bx) * 1024 + sg * 128 + dw * 8;
            *(u16x8*)&wsb[CS_OFF + ro] = cb;
            *(u16x8*)&wsb[DD_OFF + ro] = db;
            if (sb + 7 >= NS && sb < NKTILE * 32) {  // zero FR/FI tail octets
                const u16x8 zz = {0, 0, 0, 0, 0, 0, 0, 0};
                const size_t ko = ((size_t)((b * 8 + dblk) * NKTILE) + (sb >> 5)) * 1024 + sg * 128 + dw * 8;
                *(u16x8*)&wsb[FR_OFF + ko] = zz;
                *(u16x8*)&wsb[FI_OFF + ko] = zz;
            }
        }
        return;
    }

    {
        const int zb = blk - 800;
        const int b = zb >> 3;
        const int seg = zb & 7;
        const int l = len_x[b];
        const int row = 512 + seg * 64 + (tid >> 2);
        if (row >= l) {
            const int c16 = (tid & 3) * 32;
            float* p = &out[((size_t)b * SL + row) * ND + c16];
            const float4 zz = make_float4(0.f, 0.f, 0.f, 0.f);
#pragma unroll
            for (int q = 0; q < 8; ++q)
                *(float4*)&p[q * 4] = zz;
        }
        return;
    }
}

// ---------------- K2: forward DFT (split-s, 512 thr) + MLP (blocks 528..559) -----
__global__ __launch_bounds__(512) void k_fwd_mlp(
    const int* __restrict__ len_x,
    const int* __restrict__ len_y, const int* __restrict__ len_z,
    float* __restrict__ wsf, unsigned short* __restrict__ wsb,
    const float* __restrict__ W1w1, const float* __restrict__ W1b1,
    const float* __restrict__ W1w2, const float* __restrict__ W1b2,
    const float* __restrict__ B1w1, const float* __restrict__ B1b1,
    const float* __restrict__ B1w2, const float* __restrict__ B1b2,
    const float* __restrict__ W2w1, const float* __restrict__ W2b1,
    const float* __restrict__ W2w2, const float* __restrict__ W2b2,
    const float* __restrict__ B2w1, const float* __restrict__ B2b1,
    const float* __restrict__ B2w2, const float* __restrict__ B2b2) {
    const int tid = threadIdx.x;

    if (blockIdx.x >= 528) {
        // ---------- MLP path (R16 math; work gated to tid<256, barriers common) ----
        const int mb = blockIdx.x - 528;
        const int pair = mb & 1;
        const int b    = mb >> 1;

        const float* w1a = pair ? B1w1 : W1w1;  const float* b1a = pair ? B1b1 : W1b1;
        const float* w2a = pair ? B1w2 : W1w2;  const float* b2a = pair ? B1b2 : W1b2;
        const float* w1b = pair ? B2w1 : W2w1;  const float* b1b = pair ? B2b1 : W2b1;
        const float* w2b = pair ? B2w2 : W2w2;  const float* b2b = pair ? B2b2 : W2b2;

        __shared__ float c1s[ND], c2s[ND];
        __shared__ float h0[NH], h1[NH];
        __shared__ float oa[ND], ob[ND];

        if (tid < ND) {
            float s = 0.f;
            for (int ch = 0; ch < 16; ++ch)
                s += wsf[P_OFF + ((size_t)((0 * NB + b) * 16 + ch)) * ND + tid];
            c1s[tid] = s / (float)len_y[b];
        } else if (tid < 256) {
            const int d = tid - ND;
            float s = 0.f;
            for (int ch = 0; ch < 16; ++ch)
                s += wsf[P_OFF + ((size_t)((1 * NB + b) * 16 + ch)) * ND + d];
            c2s[d] = s / (float)len_z[b];
        }
        __syncthreads();

        if (tid < 256) {
            const int j = tid;
            float s0 = b1a[j], s1 = b1b[j];
            for (int i = 0; i < ND; ++i) {
                s0 = fmaf(c1s[i], w1a[i * NH + j], s0);
                s1 = fmaf(c2s[i], w1b[i * NH + j], s1);
            }
            h0[j] = 0.5f * s0 * (1.f + erff(s0 * 0.7071067811865475f));
            h1[j] = 0.5f * s1 * (1.f + erff(s1 * 0.7071067811865475f));
        }
        __syncthreads();

        if (tid < 256) {
            const bool second = tid >= ND;
            const int d = second ? tid - ND : tid;
            const float* w = second ? w2b : w2a;
            const float* hh = second ? h1 : h0;
            float s = second ? b2b[d] : b2a[d];
            for (int j = 0; j < NH; ++j)
                s = fmaf(hh[j], w[j * ND + d], s);
            if (second) ob[d] = s; else oa[d] = s;
        }
        __syncthreads();

        if (tid < ND) {
            if (pair == 0)
                wsf[SCALE_OFF + b * ND + tid] = 1.f + 0.5f * (oa[tid] + ob[tid]);
            else
                wsf[BIAS_OFF  + b * ND + tid] = 0.5f * (oa[tid] + ob[tid]);
        }
        return;
    }

    // ---------- forward DFT path: 8 waves, waves 4-7 take the upper s-half --------
    const int bid = blockIdx.x;
    const int b7 = bid & 7;
    const int q  = bid >> 3;
    const int b  = (q / 33) * 8 + b7;
    const int kbase = (q % 33) * 16;

    const int l = len_x[b];
    const int NS = (l >> 1) + 1;
    if (kbase >= NS) return;
    const float invl = 1.f / (float)l;
    const float fl = (float)l;

    __shared__ __align__(16) unsigned short Ec[16][EPAD];
    __shared__ __align__(16) unsigned short Es[16][EPAD];

    const int lane = tid & 63;
    const int wave8 = tid >> 6;        // 0..7
    const int shalf = wave8 >> 2;      // 0,1
    const int w4    = wave8 & 3;       // plays R16's "wave"
    const int lrow = lane & 15, lkg = lane >> 4;

    // E-gen: R16 verbatim, tid<256 only
    if (tid < 256) {
        const int row = tid >> 4;
        const int colbase = (tid & 15) * 36;
        const int kk = kbase + row;
#pragma unroll 6
        for (int j = 0; j < 36; j += 2) {
            unsigned cw = 0, sw = 0;
#pragma unroll
            for (int h = 0; h < 2; ++h) {
                const int sg = colbase + j + h;
                float cv = 0.f, sv = 0.f;
                if (sg < NS) {
                    const float ks = (float)(kk * sg);
                    float idxf = fmaf(-fl, floorf(ks * invl), ks);
                    idxf = (idxf < 0.f) ? idxf + fl : idxf;
                    const float rev = idxf * invl;
                    cv = hw_cos(rev);
                    sv = -hw_sin(rev);
                }
                cw |= (unsigned)f2bf(cv) << (16 * h);
                sw |= (unsigned)f2bf(sv) << (16 * h);
            }
            *(unsigned*)&Ec[row][colbase + j] = cw;
            *(unsigned*)&Es[row][colbase + j] = sw;
        }
    }
    __syncthreads();

    f32x4 accR[2], accI[2];
#pragma unroll
    for (int t = 0; t < 2; ++t) { accR[t] = 0.f; accI[t] = 0.f; }

    const size_t tb0 = ((size_t)((b * 8 + 2 * w4 + 0) * NSTILE)) * 1024 + lane * 8;
    const size_t tb1 = ((size_t)((b * 8 + 2 * w4 + 1) * NSTILE)) * 1024 + lane * 8;

    const int ntile = (NS + 31) >> 5;
    const int mid = ntile >> 1;
    const int st0 = shalf ? mid : 0;
    const int st1 = shalf ? ntile : mid;

    for (int stile = st0; stile < st1; ++stile) {
        const int s0 = stile * 32;
        const u32x4 eC = *(const u32x4*)&Ec[lrow][s0 + lkg * 8];
        const u32x4 eS = *(const u32x4*)&Es[lrow][s0 + lkg * 8];
        const u32x4 aC0 = *(const u32x4*)&wsb[CS_OFF + tb0 + (size_t)stile * 1024];
        const u32x4 aD0 = *(const u32x4*)&wsb[DD_OFF + tb0 + (size_t)stile * 1024];
        const u32x4 aC1 = *(const u32x4*)&wsb[CS_OFF + tb1 + (size_t)stile * 1024];
        const u32x4 aD1 = *(const u32x4*)&wsb[DD_OFF + tb1 + (size_t)stile * 1024];
        mfma16(accR[0], aC0, eC);
        mfma16(accI[0], aD0, eS);
        mfma16(accR[1], aC1, eC);
        mfma16(accI[1], aD1, eS);
    }

    // partial exchange: PR/PI f32 [128][16] at byte offset 4096 inside Ec/Es
    float* PR = (float*)((char*)&Ec[0][0] + 4096);
    float* PI = (float*)((char*)&Es[0][0] + 4096);

    __syncthreads();
    if (shalf == 1) {
#pragma unroll
        for (int t = 0; t < 2; ++t)
#pragma unroll
            for (int r = 0; r < 4; ++r) {
                const int drow = w4 * 32 + t * 16 + lkg * 4 + r;
                PR[drow * 16 + lrow] = accR[t][r];
                PI[drow * 16 + lrow] = accI[t][r];
            }
    }
    __syncthreads();

    // staging (R16 verbatim, by shalf==0 waves after adding the partner partials)
    unsigned short (*FRst)[16] = (unsigned short(*)[16])&Ec[0][0];
    unsigned short (*FIst)[16] = (unsigned short(*)[16])&Es[0][0];

    if (shalf == 0) {
        const int kcol = kbase + lrow;
        const float w = ((kcol == 0 || 2 * kcol == l) ? 1.f : 2.f) * invl;
#pragma unroll
        for (int t = 0; t < 2; ++t) {
#pragma unroll
            for (int r = 0; r < 4; ++r) {
                const int drow = w4 * 32 + t * 16 + lkg * 4 + r;
                const float vR = accR[t][r] + PR[drow * 16 + lrow];
                const float vI = accI[t][r] + PI[drow * 16 + lrow];
                FRst[drow][lrow] = f2bf(w * vR);
                FIst[drow][lrow] = f2bf(w * vI);
            }
        }
    }
    __syncthreads();

    if (tid < 256) {
        const int dblk = tid >> 5;
        const int kgi  = (tid >> 4) & 1;
        const int dw   = tid & 15;
        const int ktile = kbase >> 5;
        const int kg0 = (kbase & 16) ? 2 : 0;
        const size_t go = ((size_t)((b * 8 + dblk) * NKTILE) + ktile) * 1024
                        + (kg0 + kgi) * 128 + dw * 8;
        const int d = dblk * 16 + dw;
        if (kbase + 15 < NS) {
            *(u16x8*)&wsb[FR_OFF + go] = *(u16x8*)&FRst[d][kgi * 8];
            *(u16x8*)&wsb[FI_OFF + go] = *(u16x8*)&FIst[d][kgi * 8];
        } else {
            u16x8 fr, fi;
#pragma unroll
            for (int e = 0; e < 8; ++e) {
                const int kc = kbase + kgi * 8 + e;
                fr[e] = (kc < NS) ? FRst[d][kgi * 8 + e] : (unsigned short)0;
                fi[e] = (kc < NS) ? FIst[d][kgi * 8 + e] : (unsigned short)0;
            }
            *(u16x8*)&wsb[FR_OFF + go] = fr;
            *(u16x8*)&wsb[FI_OFF + go] = fi;
        }
    }
}

// ---------------- K3: inverse DFT (split-k, 512 thr) ----------------
__global__ __launch_bounds__(512) void k_inv(const int* __restrict__ len_x,
                                             const float* __restrict__ wsf,
                                             const unsigned short* __restrict__ wsb,
                                             float* __restrict__ out) {
    const int bid = blockIdx.x;
    const int b7 = bid & 7;
    const int q  = bid >> 3;
    const int b  = (q / 33) * 8 + b7;
    const int tbase = (q % 33) * 16;

    const int l = len_x[b];
    const int NS = (l >> 1) + 1;
    if (tbase >= NS) return;
    const float invl = 1.f / (float)l;
    const float fl = (float)l;

    __shared__ __align__(16) unsigned short E2c[16][EPAD];
    __shared__ __align__(16) unsigned short E2s[16][EPAD];

    const int tid = threadIdx.x;
    const int lane = tid & 63;
    const int wave8 = tid >> 6;
    const int shalf = wave8 >> 2;
    const int w4    = wave8 & 3;
    const int lrow = lane & 15, lkg = lane >> 4;

    if (tid < 256) {
        const int row = tid >> 4;
        const int colbase = (tid & 15) * 36;
        const int tt = tbase + row;
#pragma unroll 6
        for (int j = 0; j < 36; j += 2) {
            unsigned cw = 0, sw = 0;
#pragma unroll
            for (int h = 0; h < 2; ++h) {
                const int kg = colbase + j + h;
                float cv = 0.f, sv = 0.f;
                if (kg < NS) {
                    const float tk = (float)(tt * kg);
                    float idxf = fmaf(-fl, floorf(tk * invl), tk);
                    idxf = (idxf < 0.f) ? idxf + fl : idxf;
                    const float rev = idxf * invl;
                    cv = hw_cos(rev);
                    sv = hw_sin(rev);
                }
                cw |= (unsigned)f2bf(cv) << (16 * h);
                sw |= (unsigned)f2bf(sv) << (16 * h);
            }
            *(unsigned*)&E2c[row][colbase + j] = cw;
            *(unsigned*)&E2s[row][colbase + j] = sw;
        }
    }
    __syncthreads();

    const int dc0 = w4 * 32 + lrow;
    const int dc1 = w4 * 32 + 16 + lrow;
    const float sc0 = wsf[SCALE_OFF + b * ND + dc0];
    const float sc1 = wsf[SCALE_OFF + b * ND + dc1];
    const float bi0 = wsf[BIAS_OFF + b * ND + dc0];
    const float bi1 = wsf[BIAS_OFF + b * ND + dc1];

    f32x4 accA[2], accB[2];
#pragma unroll
    for (int t = 0; t < 2; ++t) { accA[t] = 0.f; accB[t] = 0.f; }

    const size_t tb0 = ((size_t)((b * 8 + 2 * w4 + 0) * NKTILE)) * 1024 + lane * 8;
    const size_t tb1 = ((size_t)((b * 8 + 2 * w4 + 1) * NKTILE)) * 1024 + lane * 8;

    const int ntile = (NS + 31) >> 5;
    const int mid = ntile >> 1;
    const int kt0 = shalf ? mid : 0;
    const int kt1 = shalf ? ntile : mid;

    for (int ktile = kt0; ktile < kt1; ++ktile) {
        const int k0 = ktile * 32;
        const u32x4 aC = *(const u32x4*)&E2c[lrow][k0 + lkg * 8];
        const u32x4 aS = *(const u32x4*)&E2s[lrow][k0 + lkg * 8];
        const u32x4 bR0 = *(const u32x4*)&wsb[FR_OFF + tb0 + (size_t)ktile * 1024];
        const u32x4 bI0 = *(const u32x4*)&wsb[FI_OFF + tb0 + (size_t)ktile * 1024];
        const u32x4 bR1 = *(const u32x4*)&wsb[FR_OFF + tb1 + (size_t)ktile * 1024];
        const u32x4 bI1 = *(const u32x4*)&wsb[FI_OFF + tb1 + (size_t)ktile * 1024];
        mfma16(accA[0], aC, bR0);
        mfma16(accB[0], aS, bI0);
        mfma16(accA[1], aC, bR1);
        mfma16(accB[1], aS, bI1);
    }

    // partial exchange: PA/PB f32 keyed by (dcol, rowidx) at byte offset 8192
    float* PA = (float*)((char*)&E2c[0][0] + 8192);
    float* PB = (float*)((char*)&E2s[0][0] + 8192);

    __syncthreads();
    if (shalf == 1) {
#pragma unroll
        for (int t = 0; t < 2; ++t)
#pragma unroll
            for (int r = 0; r < 4; ++r) {
                const int dcol = w4 * 32 + t * 16 + lrow;
                PA[dcol * 16 + lkg * 4 + r] = accA[t][r];
                PB[dcol * 16 + lkg * 4 + r] = accB[t][r];
            }
    }
    __syncthreads();

    // staging (R16 verbatim, by shalf==0 after adding partner partials)
    float (*O1)[ND] = (float(*)[ND])&E2c[0][0];
    float (*O2)[ND] = (float(*)[ND])&E2s[0][0];

    if (shalf == 0) {
#pragma unroll
        for (int t = 0; t < 2; ++t) {
            const int dcol = (t == 0) ? dc0 : dc1;
            const float sc = (t == 0) ? sc0 : sc1;
            const float bi = (t == 0) ? bi0 : bi1;
#pragma unroll
            for (int r = 0; r < 4; ++r) {
                const int ro = lkg * 4 + r;
                const float vA = accA[t][r] + PA[dcol * 16 + ro];
                const float vB = accB[t][r] + PB[dcol * 16 + ro];
                float va = (vA - vB) * sc;
                if (tbase + ro == 0) va += bi;
                O1[ro][dcol] = va;
                O2[ro][dcol] = (vA + vB) * sc;
            }
        }
    }
    __syncthreads();

    if (tid < 256) {
        const int r8 = tid >> 4;
        const int c8 = (tid & 15) * 8;
        const int trow = tbase + r8;
        if (trow < NS) {
            float* p = &out[((size_t)b * SL + trow) * ND + c8];
            *(float4*)p = *(float4*)&O1[r8][c8];
            *(float4*)(p + 4) = *(float4*)&O1[r8][c8 + 4];
            if (trow > 0 && 2 * trow != l) {
                float* q2 = &out[((size_t)b * SL + (l - trow)) * ND + c8];
                *(float4*)q2 = *(float4*)&O2[r8][c8];
                *(float4*)(q2 + 4) = *(float4*)&O2[r8][c8 + 4];
            }
        }
    }
}

extern "C" void kernel_launch(void* const* d_in, const int* in_sizes, int n_in,
                              void* d_out, int out_size, void* d_ws, size_t ws_size,
                              hipStream_t stream) {
    const float* x = (const float*)d_in[0];
    const float* y = (const float*)d_in[1];
    const float* z = (const float*)d_in[2];
    const int* len_x = (const int*)d_in[3];
    const int* len_y = (const int*)d_in[4];
    const int* len_z = (const int*)d_in[5];
    float* wsf = (float*)d_ws;
    unsigned short* wsb = (unsigned short*)d_ws;
    float* out = (float*)d_out;

    k_front<<<928, 256, 0, stream>>>(x, y, z, len_x, wsf, wsb, out);

    k_fwd_mlp<<<560, 512, 0, stream>>>(len_x, len_y, len_z, wsf, wsb,
        (const float*)d_in[6],  (const float*)d_in[7],  (const float*)d_in[8],  (const float*)d_in[9],
        (const float*)d_in[10], (const float*)d_in[11], (const float*)d_in[12], (const float*)d_in[13],
        (const float*)d_in[14], (const float*)d_in[15], (const float*)d_in[16], (const float*)d_in[17],
        (const float*)d_in[18], (const float*)d_in[19], (const float*)d_in[20], (const float*)d_in[21]);

    k_inv<<<528, 512, 0, stream>>>(len_x, wsf, wsb, out);
}

// Round 21
// 44.677 us; speedup vs baseline: 1.0445x; 1.0445x over previous
//
#include <hip/hip_runtime.h>
#include <math.h>

constexpr int NB = 16;    // batch
constexpr int SL = 1024;  // L
constexpr int ND = 128;   // D
constexpr int NH = 256;   // H
constexpr int NSTILE = 18; // s-tiles of 32 (576 slots)
constexpr int NKTILE = 17; // k-tiles of 32 (544 slots)
constexpr int EPAD = 584;  // LDS row stride for E tiles

// bf16 plane layout (ushort element indices)
// CS/DD: [b][dblk8][stile18][sg4][dw16][8]  (tile = 1024 elems)
// FR/FI: [b][dblk8][ktile17][kg4][dw16][8]
constexpr size_t PLANE_S = (size_t)NB * 8 * NSTILE * 1024;
constexpr size_t PLANE_K = (size_t)NB * 8 * NKTILE * 1024;
constexpr size_t CS_OFF = 0;
constexpr size_t DD_OFF = PLANE_S;
constexpr size_t FR_OFF = 2 * PLANE_S;
constexpr size_t FI_OFF = 2 * PLANE_S + PLANE_K;
// float scratch after bf16 region (float element indices)
constexpr size_t F32B      = PLANE_S + PLANE_K;
constexpr size_t P_OFF     = F32B;                // [2][16][16][128]
constexpr size_t SCALE_OFF = P_OFF + 2 * 16 * 16 * 128;
constexpr size_t BIAS_OFF  = SCALE_OFF + NB * ND;

typedef float          f32x4 __attribute__((ext_vector_type(4)));
typedef unsigned int   u32x4 __attribute__((ext_vector_type(4)));
typedef unsigned short u16x8 __attribute__((ext_vector_type(8)));

__device__ __forceinline__ unsigned short f2bf(float f) {
    unsigned u = __float_as_uint(f);
    return (unsigned short)((u + 0x7FFFu + ((u >> 16) & 1u)) >> 16);
}
__device__ __forceinline__ float hw_sin(float rev) {   // sin(2*pi*rev)
    float r; asm("v_sin_f32 %0, %1" : "=v"(r) : "v"(rev)); return r;
}
__device__ __forceinline__ float hw_cos(float rev) {   // cos(2*pi*rev)
    float r; asm("v_cos_f32 %0, %1" : "=v"(r) : "v"(rev)); return r;
}
__device__ __forceinline__ void mfma16(f32x4& acc, u32x4 a, u32x4 b) {
    asm("v_mfma_f32_16x16x32_bf16 %0, %1, %2, %0" : "+v"(acc) : "v"(a), "v"(b));
}
__device__ __forceinline__ float4 f4add(float4 a, float4 b) {
    return make_float4(a.x + b.x, a.y + b.y, a.z + b.z, a.w + b.w);
}

// ---------------- K1: fused front kernel (R19-identical) ----------------
__global__ __launch_bounds__(256) void k_front(const float* __restrict__ x,
                                               const float* __restrict__ y,
                                               const float* __restrict__ z,
                                               const int* __restrict__ len_x,
                                               float* __restrict__ wsf,
                                               unsigned short* __restrict__ wsb,
                                               float* __restrict__ out) {
    const int blk = blockIdx.x;
    const int tid = threadIdx.x;
    __shared__ float4 red4[256];

    if (blk < 512) {
        const int ch  = blk & 15;
        const int b   = (blk >> 4) & 15;
        const int src = blk >> 8;
        const float* base = (src == 0 ? y : z) + ((size_t)b * SL + ch * 64) * ND;
        const int dg = tid & 31;   // d-quad group
        const int tq = tid >> 5;   // 0..7
        float4 s = make_float4(0.f, 0.f, 0.f, 0.f);
#pragma unroll
        for (int j = 0; j < 8; ++j)
            s = f4add(s, *(const float4*)&base[(size_t)(tq + 8 * j) * ND + dg * 4]);
        red4[tid] = s;
        __syncthreads();
        if (tq < 4) red4[tid] = f4add(red4[tid], red4[tid + 128]);
        __syncthreads();
        if (tq < 2) red4[tid] = f4add(red4[tid], red4[tid + 64]);
        __syncthreads();
        if (tq == 0) {
            const float4 r = f4add(red4[dg], red4[dg + 32]);
            *(float4*)&wsf[P_OFF + ((size_t)((src * NB + b) * 16 + ch)) * ND + dg * 4] = r;
        }
        return;
    }

    if (blk < 800) {
        const int pb = blk - 512;
        const int bx = pb % NSTILE;   // stile
        const int b  = pb / NSTILE;
        const int l = len_x[b];
        const int NS = (l >> 1) + 1;
        const int d = tid & 127;
        const int slot = tid >> 7;
        const int dblk = d >> 4, dw = d & 15;
#pragma unroll
        for (int it = 0; it < 2; ++it) {
            const int sb = (bx * 4 + slot * 2 + it) * 8;   // octet start
            u16x8 cb, db;
#pragma unroll
            for (int j = 0; j < 8; ++j) {
                const int s = sb + j;
                float c = 0.f, dd = 0.f;
                if (s < NS) {
                    const float a = x[((size_t)b * SL + s) * ND + d];
                    float p = 0.f;
                    if (s > 0 && 2 * s != l) p = x[((size_t)b * SL + (l - s)) * ND + d];
                    c = a + p; dd = a - p;
                }
                cb[j] = f2bf(c); db[j] = f2bf(dd);
            }
            const int sg = (sb >> 3) & 3;
            const size_t ro = ((size_t)((b * 8 + dblk) * NSTILE) + bx) * 1024 + sg * 128 + dw * 8;
            *(u16x8*)&wsb[CS_OFF + ro] = cb;
            *(u16x8*)&wsb[DD_OFF + ro] = db;
            if (sb + 7 >= NS && sb < NKTILE * 32) {  // zero FR/FI tail octets
                const u16x8 zz = {0, 0, 0, 0, 0, 0, 0, 0};
                const size_t ko = ((size_t)((b * 8 + dblk) * NKTILE) + (sb >> 5)) * 1024 + sg * 128 + dw * 8;
                *(u16x8*)&wsb[FR_OFF + ko] = zz;
                *(u16x8*)&wsb[FI_OFF + ko] = zz;
            }
        }
        return;
    }

    {
        const int zb = blk - 800;
        const int b = zb >> 3;
        const int seg = zb & 7;
        const int l = len_x[b];
        const int row = 512 + seg * 64 + (tid >> 2);
        if (row >= l) {
            const int c16 = (tid & 3) * 32;
            float* p = &out[((size_t)b * SL + row) * ND + c16];
            const float4 zz = make_float4(0.f, 0.f, 0.f, 0.f);
#pragma unroll
            for (int q = 0; q < 8; ++q)
                *(float4*)&p[q * 4] = zz;
        }
        return;
    }
}

// ---------------- K2: forward DFT (32-wide ktile x split-s, 512 thr) + MLP -------
// DFT blocks [0,272): q=bid>>3 in [0,34); b=(q/17)*8+(bid&7); kbase=(q%17)*32.
// MLP blocks [272,304).
__global__ __launch_bounds__(512) void k_fwd_mlp(
    const int* __restrict__ len_x,
    const int* __restrict__ len_y, const int* __restrict__ len_z,
    float* __restrict__ wsf, unsigned short* __restrict__ wsb,
    const float* __restrict__ W1w1, const float* __restrict__ W1b1,
    const float* __restrict__ W1w2, const float* __restrict__ W1b2,
    const float* __restrict__ B1w1, const float* __restrict__ B1b1,
    const float* __restrict__ B1w2, const float* __restrict__ B1b2,
    const float* __restrict__ W2w1, const float* __restrict__ W2b1,
    const float* __restrict__ W2w2, const float* __restrict__ W2b2,
    const float* __restrict__ B2w1, const float* __restrict__ B2b1,
    const float* __restrict__ B2w2, const float* __restrict__ B2b2) {
    const int tid = threadIdx.x;

    if (blockIdx.x >= 272) {
        // ---------- MLP path (R20-identical) ----------
        const int mb = blockIdx.x - 272;
        const int pair = mb & 1;
        const int b    = mb >> 1;

        const float* w1a = pair ? B1w1 : W1w1;  const float* b1a = pair ? B1b1 : W1b1;
        const float* w2a = pair ? B1w2 : W1w2;  const float* b2a = pair ? B1b2 : W1b2;
        const float* w1b = pair ? B2w1 : W2w1;  const float* b1b = pair ? B2b1 : W2b1;
        const float* w2b = pair ? B2w2 : W2w2;  const float* b2b = pair ? B2b2 : W2b2;

        __shared__ float c1s[ND], c2s[ND];
        __shared__ float h0[NH], h1[NH];
        __shared__ float oa[ND], ob[ND];

        if (tid < ND) {
            float s = 0.f;
            for (int ch = 0; ch < 16; ++ch)
                s += wsf[P_OFF + ((size_t)((0 * NB + b) * 16 + ch)) * ND + tid];
            c1s[tid] = s / (float)len_y[b];
        } else if (tid < 256) {
            const int d = tid - ND;
            float s = 0.f;
            for (int ch = 0; ch < 16; ++ch)
                s += wsf[P_OFF + ((size_t)((1 * NB + b) * 16 + ch)) * ND + d];
            c2s[d] = s / (float)len_z[b];
        }
        __syncthreads();

        if (tid < 256) {
            const int j = tid;
            float s0 = b1a[j], s1 = b1b[j];
            for (int i = 0; i < ND; ++i) {
                s0 = fmaf(c1s[i], w1a[i * NH + j], s0);
                s1 = fmaf(c2s[i], w1b[i * NH + j], s1);
            }
            h0[j] = 0.5f * s0 * (1.f + erff(s0 * 0.7071067811865475f));
            h1[j] = 0.5f * s1 * (1.f + erff(s1 * 0.7071067811865475f));
        }
        __syncthreads();

        if (tid < 256) {
            const bool second = tid >= ND;
            const int d = second ? tid - ND : tid;
            const float* w = second ? w2b : w2a;
            const float* hh = second ? h1 : h0;
            float s = second ? b2b[d] : b2a[d];
            for (int j = 0; j < NH; ++j)
                s = fmaf(hh[j], w[j * ND + d], s);
            if (second) ob[d] = s; else oa[d] = s;
        }
        __syncthreads();

        if (tid < ND) {
            if (pair == 0)
                wsf[SCALE_OFF + b * ND + tid] = 1.f + 0.5f * (oa[tid] + ob[tid]);
            else
                wsf[BIAS_OFF  + b * ND + tid] = 0.5f * (oa[tid] + ob[tid]);
        }
        return;
    }

    // ---------- forward DFT: 2 ktiles/block, waves 4-7 take upper s-half ----------
    const int bid = blockIdx.x;
    const int b7 = bid & 7;
    const int q  = bid >> 3;
    const int b  = (q / 17) * 8 + b7;
    const int kbase = (q % 17) * 32;

    const int l = len_x[b];
    const int NS = (l >> 1) + 1;
    if (kbase >= NS) return;
    const float invl = 1.f / (float)l;
    const float fl = (float)l;

    __shared__ __align__(16) unsigned short Ec[2][16][EPAD];
    __shared__ __align__(16) unsigned short Es[2][16][EPAD];

    const int lane = tid & 63;
    const int wave8 = tid >> 6;        // 0..7
    const int shalf = wave8 >> 2;      // 0,1
    const int w4    = wave8 & 3;       // R16's "wave"
    const int lrow = lane & 15, lkg = lane >> 4;

    // E-gen: 512 thr = 2 groups of 256; group pp does tile pp (R16 inner verbatim)
    {
        const int pp = tid >> 8;
        const int t2 = tid & 255;
        const int row = t2 >> 4;
        const int colbase = (t2 & 15) * 36;
        const int kk = kbase + pp * 16 + row;
#pragma unroll 6
        for (int j = 0; j < 36; j += 2) {
            unsigned cw = 0, sw = 0;
#pragma unroll
            for (int h = 0; h < 2; ++h) {
                const int sg = colbase + j + h;
                float cv = 0.f, sv = 0.f;
                if (sg < NS) {
                    const float ks = (float)(kk * sg);
                    float idxf = fmaf(-fl, floorf(ks * invl), ks);
                    idxf = (idxf < 0.f) ? idxf + fl : idxf;
                    const float rev = idxf * invl;
                    cv = hw_cos(rev);
                    sv = -hw_sin(rev);
                }
                cw |= (unsigned)f2bf(cv) << (16 * h);
                sw |= (unsigned)f2bf(sv) << (16 * h);
            }
            *(unsigned*)&Ec[pp][row][colbase + j] = cw;
            *(unsigned*)&Es[pp][row][colbase + j] = sw;
        }
    }
    __syncthreads();

    f32x4 accR[2][2], accI[2][2];   // [t dblk-half][p ktile]
#pragma unroll
    for (int t = 0; t < 2; ++t)
#pragma unroll
        for (int p = 0; p < 2; ++p) { accR[t][p] = 0.f; accI[t][p] = 0.f; }

    const size_t tb0 = ((size_t)((b * 8 + 2 * w4 + 0) * NSTILE)) * 1024 + lane * 8;
    const size_t tb1 = ((size_t)((b * 8 + 2 * w4 + 1) * NSTILE)) * 1024 + lane * 8;

    const int ntile = (NS + 31) >> 5;
    const int mid = ntile >> 1;
    const int st0 = shalf ? mid : 0;
    const int st1 = shalf ? ntile : mid;

    for (int stile = st0; stile < st1; ++stile) {
        const int s0 = stile * 32;
        const u32x4 eC0 = *(const u32x4*)&Ec[0][lrow][s0 + lkg * 8];
        const u32x4 eS0 = *(const u32x4*)&Es[0][lrow][s0 + lkg * 8];
        const u32x4 eC1 = *(const u32x4*)&Ec[1][lrow][s0 + lkg * 8];
        const u32x4 eS1 = *(const u32x4*)&Es[1][lrow][s0 + lkg * 8];
        const u32x4 aC0 = *(const u32x4*)&wsb[CS_OFF + tb0 + (size_t)stile * 1024];
        const u32x4 aD0 = *(const u32x4*)&wsb[DD_OFF + tb0 + (size_t)stile * 1024];
        const u32x4 aC1 = *(const u32x4*)&wsb[CS_OFF + tb1 + (size_t)stile * 1024];
        const u32x4 aD1 = *(const u32x4*)&wsb[DD_OFF + tb1 + (size_t)stile * 1024];
        mfma16(accR[0][0], aC0, eC0);
        mfma16(accI[0][0], aD0, eS0);
        mfma16(accR[1][0], aC1, eC0);
        mfma16(accI[1][0], aD1, eS0);
        mfma16(accR[0][1], aC0, eC1);
        mfma16(accI[0][1], aD0, eS1);
        mfma16(accR[1][1], aC1, eC1);
        mfma16(accI[1][1], aD1, eS1);
    }

    // partial exchange: PR/PI f32 [2 p][128 drow][16 lrow], at +4096 inside Ec/Es
    float* PR = (float*)((char*)&Ec[0][0][0] + 4096);
    float* PI = (float*)((char*)&Es[0][0][0] + 4096);

    __syncthreads();
    if (shalf == 1) {
#pragma unroll
        for (int t = 0; t < 2; ++t)
#pragma unroll
            for (int p = 0; p < 2; ++p)
#pragma unroll
                for (int r = 0; r < 4; ++r) {
                    const int drow = w4 * 32 + t * 16 + lkg * 4 + r;
                    PR[(p * 128 + drow) * 16 + lrow] = accR[t][p][r];
                    PI[(p * 128 + drow) * 16 + lrow] = accI[t][p][r];
                }
    }
    __syncthreads();

    // staging + write, per ktile p (R16 epilogue verbatim with kb2)
    unsigned short (*FRst)[16] = (unsigned short(*)[16])&Ec[0][0][0];
    unsigned short (*FIst)[16] = (unsigned short(*)[16])&Es[0][0][0];

#pragma unroll
    for (int p = 0; p < 2; ++p) {
        const int kb2 = kbase + p * 16;
        if (p) __syncthreads();
        if (shalf == 0) {
            const int kcol = kb2 + lrow;
            const float w = ((kcol == 0 || 2 * kcol == l) ? 1.f : 2.f) * invl;
#pragma unroll
            for (int t = 0; t < 2; ++t) {
#pragma unroll
                for (int r = 0; r < 4; ++r) {
                    const int drow = w4 * 32 + t * 16 + lkg * 4 + r;
                    const float vR = accR[t][p][r] + PR[(p * 128 + drow) * 16 + lrow];
                    const float vI = accI[t][p][r] + PI[(p * 128 + drow) * 16 + lrow];
                    FRst[drow][lrow] = f2bf(w * vR);
                    FIst[drow][lrow] = f2bf(w * vI);
                }
            }
        }
        __syncthreads();

        if (tid < 256) {
            const int dblk = tid >> 5;
            const int kgi  = (tid >> 4) & 1;
            const int dw   = tid & 15;
            const int ktile = kb2 >> 5;
            const int kg0 = (kb2 & 16) ? 2 : 0;
            const size_t go = ((size_t)((b * 8 + dblk) * NKTILE) + ktile) * 1024
                            + (kg0 + kgi) * 128 + dw * 8;
            const int d = dblk * 16 + dw;
            if (kb2 + 15 < NS) {
                *(u16x8*)&wsb[FR_OFF + go] = *(u16x8*)&FRst[d][kgi * 8];
                *(u16x8*)&wsb[FI_OFF + go] = *(u16x8*)&FIst[d][kgi * 8];
            } else {
                u16x8 fr, fi;
#pragma unroll
                for (int e = 0; e < 8; ++e) {
                    const int kc = kb2 + kgi * 8 + e;
                    fr[e] = (kc < NS) ? FRst[d][kgi * 8 + e] : (unsigned short)0;
                    fi[e] = (kc < NS) ? FIst[d][kgi * 8 + e] : (unsigned short)0;
                }
                *(u16x8*)&wsb[FR_OFF + go] = fr;
                *(u16x8*)&wsb[FI_OFF + go] = fi;
            }
        }
    }
}

// ---------------- K3: inverse DFT (32-wide ttile x split-k, 512 thr) -------------
__global__ __launch_bounds__(512) void k_inv(const int* __restrict__ len_x,
                                             const float* __restrict__ wsf,
                                             const unsigned short* __restrict__ wsb,
                                             float* __restrict__ out) {
    const int bid = blockIdx.x;
    const int b7 = bid & 7;
    const int q  = bid >> 3;
    const int b  = (q / 17) * 8 + b7;
    const int tbase = (q % 17) * 32;

    const int l = len_x[b];
    const int NS = (l >> 1) + 1;
    if (tbase >= NS) return;
    const float invl = 1.f / (float)l;
    const float fl = (float)l;

    __shared__ __align__(16) unsigned short E2c[2][16][EPAD];
    __shared__ __align__(16) unsigned short E2s[2][16][EPAD];

    const int tid = threadIdx.x;
    const int lane = tid & 63;
    const int wave8 = tid >> 6;
    const int shalf = wave8 >> 2;
    const int w4    = wave8 & 3;
    const int lrow = lane & 15, lkg = lane >> 4;

    {
        const int pp = tid >> 8;
        const int t2 = tid & 255;
        const int row = t2 >> 4;
        const int colbase = (t2 & 15) * 36;
        const int tt = tbase + pp * 16 + row;
#pragma unroll 6
        for (int j = 0; j < 36; j += 2) {
            unsigned cw = 0, sw = 0;
#pragma unroll
            for (int h = 0; h < 2; ++h) {
                const int kg = colbase + j + h;
                float cv = 0.f, sv = 0.f;
                if (kg < NS) {
                    const float tk = (float)(tt * kg);
                    float idxf = fmaf(-fl, floorf(tk * invl), tk);
                    idxf = (idxf < 0.f) ? idxf + fl : idxf;
                    const float rev = idxf * invl;
                    cv = hw_cos(rev);
                    sv = hw_sin(rev);
                }
                cw |= (unsigned)f2bf(cv) << (16 * h);
                sw |= (unsigned)f2bf(sv) << (16 * h);
            }
            *(unsigned*)&E2c[pp][row][colbase + j] = cw;
            *(unsigned*)&E2s[pp][row][colbase + j] = sw;
        }
    }
    __syncthreads();

    const int dc0 = w4 * 32 + lrow;
    const int dc1 = w4 * 32 + 16 + lrow;
    const float sc0 = wsf[SCALE_OFF + b * ND + dc0];
    const float sc1 = wsf[SCALE_OFF + b * ND + dc1];
    const float bi0 = wsf[BIAS_OFF + b * ND + dc0];
    const float bi1 = wsf[BIAS_OFF + b * ND + dc1];

    f32x4 accA[2][2], accB[2][2];   // [t dblk-half][p ttile]
#pragma unroll
    for (int t = 0; t < 2; ++t)
#pragma unroll
        for (int p = 0; p < 2; ++p) { accA[t][p] = 0.f; accB[t][p] = 0.f; }

    const size_t tb0 = ((size_t)((b * 8 + 2 * w4 + 0) * NKTILE)) * 1024 + lane * 8;
    const size_t tb1 = ((size_t)((b * 8 + 2 * w4 + 1) * NKTILE)) * 1024 + lane * 8;

    const int ntile = (NS + 31) >> 5;
    const int mid = ntile >> 1;
    const int kt0 = shalf ? mid : 0;
    const int kt1 = shalf ? ntile : mid;

    for (int ktile = kt0; ktile < kt1; ++ktile) {
        const int k0 = ktile * 32;
        const u32x4 aC0 = *(const u32x4*)&E2c[0][lrow][k0 + lkg * 8];
        const u32x4 aS0 = *(const u32x4*)&E2s[0][lrow][k0 + lkg * 8];
        const u32x4 aC1 = *(const u32x4*)&E2c[1][lrow][k0 + lkg * 8];
        const u32x4 aS1 = *(const u32x4*)&E2s[1][lrow][k0 + lkg * 8];
        const u32x4 bR0 = *(const u32x4*)&wsb[FR_OFF + tb0 + (size_t)ktile * 1024];
        const u32x4 bI0 = *(const u32x4*)&wsb[FI_OFF + tb0 + (size_t)ktile * 1024];
        const u32x4 bR1 = *(const u32x4*)&wsb[FR_OFF + tb1 + (size_t)ktile * 1024];
        const u32x4 bI1 = *(const u32x4*)&wsb[FI_OFF + tb1 + (size_t)ktile * 1024];
        mfma16(accA[0][0], aC0, bR0);
        mfma16(accB[0][0], aS0, bI0);
        mfma16(accA[1][0], aC0, bR1);
        mfma16(accB[1][0], aS0, bI1);
        mfma16(accA[0][1], aC1, bR0);
        mfma16(accB[0][1], aS1, bI0);
        mfma16(accA[1][1], aC1, bR1);
        mfma16(accB[1][1], aS1, bI1);
    }

    // partial exchange: PA/PB f32 [2 p][128 dcol][16 ro], at +8192 inside E2c/E2s
    float* PA = (float*)((char*)&E2c[0][0][0] + 8192);
    float* PB = (float*)((char*)&E2s[0][0][0] + 8192);

    __syncthreads();
    if (shalf == 1) {
#pragma unroll
        for (int t = 0; t < 2; ++t)
#pragma unroll
            for (int p = 0; p < 2; ++p)
#pragma unroll
                for (int r = 0; r < 4; ++r) {
                    const int dcol = w4 * 32 + t * 16 + lrow;
                    PA[(p * 128 + dcol) * 16 + lkg * 4 + r] = accA[t][p][r];
                    PB[(p * 128 + dcol) * 16 + lkg * 4 + r] = accB[t][p][r];
                }
    }
    __syncthreads();

    // staging + write, per ttile p (R16 epilogue verbatim with tb2)
    float (*O1)[ND] = (float(*)[ND])&E2c[0][0][0];
    float (*O2)[ND] = (float(*)[ND])&E2s[0][0][0];

#pragma unroll
    for (int p = 0; p < 2; ++p) {
        const int tb2 = tbase + p * 16;
        if (p) __syncthreads();
        if (shalf == 0) {
#pragma unroll
            for (int t = 0; t < 2; ++t) {
                const int dcol = (t == 0) ? dc0 : dc1;
                const float sc = (t == 0) ? sc0 : sc1;
                const float bi = (t == 0) ? bi0 : bi1;
#pragma unroll
                for (int r = 0; r < 4; ++r) {
                    const int ro = lkg * 4 + r;
                    const float vA = accA[t][p][r] + PA[(p * 128 + dcol) * 16 + ro];
                    const float vB = accB[t][p][r] + PB[(p * 128 + dcol) * 16 + ro];
                    float va = (vA - vB) * sc;
                    if (tb2 + ro == 0) va += bi;
                    O1[ro][dcol] = va;
                    O2[ro][dcol] = (vA + vB) * sc;
                }
            }
        }
        __syncthreads();

        if (tid < 256) {
            const int r8 = tid >> 4;
            const int c8 = (tid & 15) * 8;
            const int trow = tb2 + r8;
            if (trow < NS) {
                float* pp = &out[((size_t)b * SL + trow) * ND + c8];
                *(float4*)pp = *(float4*)&O1[r8][c8];
                *(float4*)(pp + 4) = *(float4*)&O1[r8][c8 + 4];
                if (trow > 0 && 2 * trow != l) {
                    float* q2 = &out[((size_t)b * SL + (l - trow)) * ND + c8];
                    *(float4*)q2 = *(float4*)&O2[r8][c8];
                    *(float4*)(q2 + 4) = *(float4*)&O2[r8][c8 + 4];
                }
            }
        }
    }
}

extern "C" void kernel_launch(void* const* d_in, const int* in_sizes, int n_in,
                              void* d_out, int out_size, void* d_ws, size_t ws_size,
                              hipStream_t stream) {
    const float* x = (const float*)d_in[0];
    const float* y = (const float*)d_in[1];
    const float* z = (const float*)d_in[2];
    const int* len_x = (const int*)d_in[3];
    const int* len_y = (const int*)d_in[4];
    const int* len_z = (const int*)d_in[5];
    float* wsf = (float*)d_ws;
    unsigned short* wsb = (unsigned short*)d_ws;
    float* out = (float*)d_out;

    k_front<<<928, 256, 0, stream>>>(x, y, z, len_x, wsf, wsb, out);

    k_fwd_mlp<<<304, 512, 0, stream>>>(len_x, len_y, len_z, wsf, wsb,
        (const float*)d_in[6],  (const float*)d_in[7],  (const float*)d_in[8],  (const float*)d_in[9],
        (const float*)d_in[10], (const float*)d_in[11], (const float*)d_in[12], (const float*)d_in[13],
        (const float*)d_in[14], (const float*)d_in[15], (const float*)d_in[16], (const float*)d_in[17],
        (const float*)d_in[18], (const float*)d_in[19], (const float*)d_in[20], (const float*)d_in[21]);

    k_inv<<<272, 512, 0, stream>>>(len_x, wsf, wsb, out);
}

// Round 22
// 43.254 us; speedup vs baseline: 1.0788x; 1.0329x over previous
//
#include <hip/hip_runtime.h>
#include <math.h>

constexpr int NB = 16;    // batch
constexpr int SL = 1024;  // L
constexpr int ND = 128;   // D
constexpr int NH = 256;   // H
constexpr int NSTILE = 18; // s-tiles of 32 (576 slots)
constexpr int NKTILE = 17; // k-tiles of 32 (544 slots)
constexpr int EPAD = 584;  // LDS row stride for E tiles

// bf16 plane layout (ushort element indices)
// CS/DD: [b][dblk8][stile18][sg4][dw16][8]  (tile = 1024 elems)
// FR/FI: [b][dblk8][ktile17][kg4][dw16][8]
constexpr size_t PLANE_S = (size_t)NB * 8 * NSTILE * 1024;
constexpr size_t PLANE_K = (size_t)NB * 8 * NKTILE * 1024;
constexpr size_t CS_OFF = 0;
constexpr size_t DD_OFF = PLANE_S;
constexpr size_t FR_OFF = 2 * PLANE_S;
constexpr size_t FI_OFF = 2 * PLANE_S + PLANE_K;
// float scratch after bf16 region (float element indices)
constexpr size_t F32B      = PLANE_S + PLANE_K;
constexpr size_t P_OFF     = F32B;                // [2][16][16][128]
constexpr size_t SCALE_OFF = P_OFF + 2 * 16 * 16 * 128;
constexpr size_t BIAS_OFF  = SCALE_OFF + NB * ND;

typedef float          f32x4 __attribute__((ext_vector_type(4)));
typedef unsigned int   u32x4 __attribute__((ext_vector_type(4)));
typedef unsigned short u16x8 __attribute__((ext_vector_type(8)));

__device__ __forceinline__ unsigned short f2bf(float f) {
    unsigned u = __float_as_uint(f);
    return (unsigned short)((u + 0x7FFFu + ((u >> 16) & 1u)) >> 16);
}
__device__ __forceinline__ float hw_sin(float rev) {   // sin(2*pi*rev)
    float r; asm("v_sin_f32 %0, %1" : "=v"(r) : "v"(rev)); return r;
}
__device__ __forceinline__ float hw_cos(float rev) {   // cos(2*pi*rev)
    float r; asm("v_cos_f32 %0, %1" : "=v"(r) : "v"(rev)); return r;
}
__device__ __forceinline__ void mfma16(f32x4& acc, u32x4 a, u32x4 b) {
    asm("v_mfma_f32_16x16x32_bf16 %0, %1, %2, %0" : "+v"(acc) : "v"(a), "v"(b));
}
__device__ __forceinline__ float4 f4add(float4 a, float4 b) {
    return make_float4(a.x + b.x, a.y + b.y, a.z + b.z, a.w + b.w);
}

// ---------------- K1: fused front kernel (R19-identical) ----------------
__global__ __launch_bounds__(256) void k_front(const float* __restrict__ x,
                                               const float* __restrict__ y,
                                               const float* __restrict__ z,
                                               const int* __restrict__ len_x,
                                               float* __restrict__ wsf,
                                               unsigned short* __restrict__ wsb,
                                               float* __restrict__ out) {
    const int blk = blockIdx.x;
    const int tid = threadIdx.x;
    __shared__ float4 red4[256];

    if (blk < 512) {
        const int ch  = blk & 15;
        const int b   = (blk >> 4) & 15;
        const int src = blk >> 8;
        const float* base = (src == 0 ? y : z) + ((size_t)b * SL + ch * 64) * ND;
        const int dg = tid & 31;   // d-quad group
        const int tq = tid >> 5;   // 0..7
        float4 s = make_float4(0.f, 0.f, 0.f, 0.f);
#pragma unroll
        for (int j = 0; j < 8; ++j)
            s = f4add(s, *(const float4*)&base[(size_t)(tq + 8 * j) * ND + dg * 4]);
        red4[tid] = s;
        __syncthreads();
        if (tq < 4) red4[tid] = f4add(red4[tid], red4[tid + 128]);
        __syncthreads();
        if (tq < 2) red4[tid] = f4add(red4[tid], red4[tid + 64]);
        __syncthreads();
        if (tq == 0) {
            const float4 r = f4add(red4[dg], red4[dg + 32]);
            *(float4*)&wsf[P_OFF + ((size_t)((src * NB + b) * 16 + ch)) * ND + dg * 4] = r;
        }
        return;
    }

    if (blk < 800) {
        const int pb = blk - 512;
        const int bx = pb % NSTILE;   // stile
        const int b  = pb / NSTILE;
        const int l = len_x[b];
        const int NS = (l >> 1) + 1;
        const int d = tid & 127;
        const int slot = tid >> 7;
        const int dblk = d >> 4, dw = d & 15;
#pragma unroll
        for (int it = 0; it < 2; ++it) {
            const int sb = (bx * 4 + slot * 2 + it) * 8;   // octet start
            u16x8 cb, db;
#pragma unroll
            for (int j = 0; j < 8; ++j) {
                const int s = sb + j;
                float c = 0.f, dd = 0.f;
                if (s < NS) {
                    const float a = x[((size_t)b * SL + s) * ND + d];
                    float p = 0.f;
                    if (s > 0 && 2 * s != l) p = x[((size_t)b * SL + (l - s)) * ND + d];
                    c = a + p; dd = a - p;
                }
                cb[j] = f2bf(c); db[j] = f2bf(dd);
            }
            const int sg = (sb >> 3) & 3;
            const size_t ro = ((size_t)((b * 8 + dblk) * NSTILE) + bx) * 1024 + sg * 128 + dw * 8;
            *(u16x8*)&wsb[CS_OFF + ro] = cb;
            *(u16x8*)&wsb[DD_OFF + ro] = db;
            if (sb + 7 >= NS && sb < NKTILE * 32) {  // zero FR/FI tail octets
                const u16x8 zz = {0, 0, 0, 0, 0, 0, 0, 0};
                const size_t ko = ((size_t)((b * 8 + dblk) * NKTILE) + (sb >> 5)) * 1024 + sg * 128 + dw * 8;
                *(u16x8*)&wsb[FR_OFF + ko] = zz;
                *(u16x8*)&wsb[FI_OFF + ko] = zz;
            }
        }
        return;
    }

    {
        const int zb = blk - 800;
        const int b = zb >> 3;
        const int seg = zb & 7;
        const int l = len_x[b];
        const int row = 512 + seg * 64 + (tid >> 2);
        if (row >= l) {
            const int c16 = (tid & 3) * 32;
            float* p = &out[((size_t)b * SL + row) * ND + c16];
            const float4 zz = make_float4(0.f, 0.f, 0.f, 0.f);
#pragma unroll
            for (int q = 0; q < 8; ++q)
                *(float4*)&p[q * 4] = zz;
        }
        return;
    }
}

// ---------------- K2: forward DFT (32-wide ktile x split-s, 512 thr) + MLP -------
// DFT blocks [0,272): q=bid>>3 in [0,34); b=(q/17)*8+(bid&7); kbase=(q%17)*32.
// MLP blocks [272,304).
__global__ __launch_bounds__(512) void k_fwd_mlp(
    const int* __restrict__ len_x,
    const int* __restrict__ len_y, const int* __restrict__ len_z,
    float* __restrict__ wsf, unsigned short* __restrict__ wsb,
    const float* __restrict__ W1w1, const float* __restrict__ W1b1,
    const float* __restrict__ W1w2, const float* __restrict__ W1b2,
    const float* __restrict__ B1w1, const float* __restrict__ B1b1,
    const float* __restrict__ B1w2, const float* __restrict__ B1b2,
    const float* __restrict__ W2w1, const float* __restrict__ W2b1,
    const float* __restrict__ W2w2, const float* __restrict__ W2b2,
    const float* __restrict__ B2w1, const float* __restrict__ B2b1,
    const float* __restrict__ B2w2, const float* __restrict__ B2b2) {
    const int tid = threadIdx.x;

    if (blockIdx.x >= 272) {
        // ---------- MLP path (R20-identical) ----------
        const int mb = blockIdx.x - 272;
        const int pair = mb & 1;
        const int b    = mb >> 1;

        const float* w1a = pair ? B1w1 : W1w1;  const float* b1a = pair ? B1b1 : W1b1;
        const float* w2a = pair ? B1w2 : W1w2;  const float* b2a = pair ? B1b2 : W1b2;
        const float* w1b = pair ? B2w1 : W2w1;  const float* b1b = pair ? B2b1 : W2b1;
        const float* w2b = pair ? B2w2 : W2w2;  const float* b2b = pair ? B2b2 : W2b2;

        __shared__ float c1s[ND], c2s[ND];
        __shared__ float h0[NH], h1[NH];
        __shared__ float oa[ND], ob[ND];

        if (tid < ND) {
            float s = 0.f;
            for (int ch = 0; ch < 16; ++ch)
                s += wsf[P_OFF + ((size_t)((0 * NB + b) * 16 + ch)) * ND + tid];
            c1s[tid] = s / (float)len_y[b];
        } else if (tid < 256) {
            const int d = tid - ND;
            float s = 0.f;
            for (int ch = 0; ch < 16; ++ch)
                s += wsf[P_OFF + ((size_t)((1 * NB + b) * 16 + ch)) * ND + d];
            c2s[d] = s / (float)len_z[b];
        }
        __syncthreads();

        if (tid < 256) {
            const int j = tid;
            float s0 = b1a[j], s1 = b1b[j];
            for (int i = 0; i < ND; ++i) {
                s0 = fmaf(c1s[i], w1a[i * NH + j], s0);
                s1 = fmaf(c2s[i], w1b[i * NH + j], s1);
            }
            h0[j] = 0.5f * s0 * (1.f + erff(s0 * 0.7071067811865475f));
            h1[j] = 0.5f * s1 * (1.f + erff(s1 * 0.7071067811865475f));
        }
        __syncthreads();

        if (tid < 256) {
            const bool second = tid >= ND;
            const int d = second ? tid - ND : tid;
            const float* w = second ? w2b : w2a;
            const float* hh = second ? h1 : h0;
            float s = second ? b2b[d] : b2a[d];
            for (int j = 0; j < NH; ++j)
                s = fmaf(hh[j], w[j * ND + d], s);
            if (second) ob[d] = s; else oa[d] = s;
        }
        __syncthreads();

        if (tid < ND) {
            if (pair == 0)
                wsf[SCALE_OFF + b * ND + tid] = 1.f + 0.5f * (oa[tid] + ob[tid]);
            else
                wsf[BIAS_OFF  + b * ND + tid] = 0.5f * (oa[tid] + ob[tid]);
        }
        return;
    }

    // ---------- forward DFT: 2 ktiles/block, waves 4-7 take upper s-half ----------
    const int bid = blockIdx.x;
    const int b7 = bid & 7;
    const int q  = bid >> 3;
    const int b  = (q / 17) * 8 + b7;
    const int kbase = (q % 17) * 32;

    const int l = len_x[b];
    const int NS = (l >> 1) + 1;
    if (kbase >= NS) return;
    const float invl = 1.f / (float)l;
    const float fl = (float)l;

    __shared__ __align__(16) unsigned short Ec[2][16][EPAD];
    __shared__ __align__(16) unsigned short Es[2][16][EPAD];

    const int lane = tid & 63;
    const int wave8 = tid >> 6;        // 0..7
    const int shalf = wave8 >> 2;      // 0,1
    const int w4    = wave8 & 3;       // R16's "wave"
    const int lrow = lane & 15, lkg = lane >> 4;

    // E-gen via per-thread recurrence: seed at s=colbase, step e^{-2pi i k/l}
    {
        const int pp = tid >> 8;
        const int t2 = tid & 255;
        const int row = t2 >> 4;
        const int colbase = (t2 & 15) * 36;
        const int kk = kbase + pp * 16 + row;   // kk < l (active blocks)
        const float ks = (float)(kk * colbase);
        float idxf = fmaf(-fl, floorf(ks * invl), ks);
        idxf = (idxf < 0.f) ? idxf + fl : idxf;
        const float rev0 = idxf * invl;
        float cr = hw_cos(rev0);
        float ci = -hw_sin(rev0);                 // e^{-i th k s0}
        const float revs = (float)kk * invl;      // in [0,1)
        const float spc = hw_cos(revs);
        const float sps = -hw_sin(revs);          // e^{-i th k}
#pragma unroll 6
        for (int j = 0; j < 36; j += 2) {
            unsigned cw = 0, sw = 0;
#pragma unroll
            for (int h = 0; h < 2; ++h) {
                const int sg = colbase + j + h;
                if (sg < NS) {
                    cw |= (unsigned)f2bf(cr) << (16 * h);
                    sw |= (unsigned)f2bf(ci) << (16 * h);
                }
                const float ncr = fmaf(cr, spc, -ci * sps);
                const float nci = fmaf(cr, sps, ci * spc);
                cr = ncr; ci = nci;
            }
            *(unsigned*)&Ec[pp][row][colbase + j] = cw;
            *(unsigned*)&Es[pp][row][colbase + j] = sw;
        }
    }
    __syncthreads();

    f32x4 accR[2][2], accI[2][2];   // [t dblk-half][p ktile]
#pragma unroll
    for (int t = 0; t < 2; ++t)
#pragma unroll
        for (int p = 0; p < 2; ++p) { accR[t][p] = 0.f; accI[t][p] = 0.f; }

    const size_t tb0 = ((size_t)((b * 8 + 2 * w4 + 0) * NSTILE)) * 1024 + lane * 8;
    const size_t tb1 = ((size_t)((b * 8 + 2 * w4 + 1) * NSTILE)) * 1024 + lane * 8;

    const int ntile = (NS + 31) >> 5;
    const int mid = ntile >> 1;
    const int st0 = shalf ? mid : 0;
    const int st1 = shalf ? ntile : mid;

#pragma unroll 2
    for (int stile = st0; stile < st1; ++stile) {
        const int s0 = stile * 32;
        const u32x4 eC0 = *(const u32x4*)&Ec[0][lrow][s0 + lkg * 8];
        const u32x4 eS0 = *(const u32x4*)&Es[0][lrow][s0 + lkg * 8];
        const u32x4 eC1 = *(const u32x4*)&Ec[1][lrow][s0 + lkg * 8];
        const u32x4 eS1 = *(const u32x4*)&Es[1][lrow][s0 + lkg * 8];
        const u32x4 aC0 = *(const u32x4*)&wsb[CS_OFF + tb0 + (size_t)stile * 1024];
        const u32x4 aD0 = *(const u32x4*)&wsb[DD_OFF + tb0 + (size_t)stile * 1024];
        const u32x4 aC1 = *(const u32x4*)&wsb[CS_OFF + tb1 + (size_t)stile * 1024];
        const u32x4 aD1 = *(const u32x4*)&wsb[DD_OFF + tb1 + (size_t)stile * 1024];
        mfma16(accR[0][0], aC0, eC0);
        mfma16(accI[0][0], aD0, eS0);
        mfma16(accR[1][0], aC1, eC0);
        mfma16(accI[1][0], aD1, eS0);
        mfma16(accR[0][1], aC0, eC1);
        mfma16(accI[0][1], aD0, eS1);
        mfma16(accR[1][1], aC1, eC1);
        mfma16(accI[1][1], aD1, eS1);
    }

    // partial exchange: PR/PI f32 [2 p][128 drow][16 lrow], at +4096 inside Ec/Es
    float* PR = (float*)((char*)&Ec[0][0][0] + 4096);
    float* PI = (float*)((char*)&Es[0][0][0] + 4096);

    __syncthreads();
    if (shalf == 1) {
#pragma unroll
        for (int t = 0; t < 2; ++t)
#pragma unroll
            for (int p = 0; p < 2; ++p)
#pragma unroll
                for (int r = 0; r < 4; ++r) {
                    const int drow = w4 * 32 + t * 16 + lkg * 4 + r;
                    PR[(p * 128 + drow) * 16 + lrow] = accR[t][p][r];
                    PI[(p * 128 + drow) * 16 + lrow] = accI[t][p][r];
                }
    }
    __syncthreads();

    // staging + write, per ktile p (R16 epilogue verbatim with kb2)
    unsigned short (*FRst)[16] = (unsigned short(*)[16])&Ec[0][0][0];
    unsigned short (*FIst)[16] = (unsigned short(*)[16])&Es[0][0][0];

#pragma unroll
    for (int p = 0; p < 2; ++p) {
        const int kb2 = kbase + p * 16;
        if (p) __syncthreads();
        if (shalf == 0) {
            const int kcol = kb2 + lrow;
            const float w = ((kcol == 0 || 2 * kcol == l) ? 1.f : 2.f) * invl;
#pragma unroll
            for (int t = 0; t < 2; ++t) {
#pragma unroll
                for (int r = 0; r < 4; ++r) {
                    const int drow = w4 * 32 + t * 16 + lkg * 4 + r;
                    const float vR = accR[t][p][r] + PR[(p * 128 + drow) * 16 + lrow];
                    const float vI = accI[t][p][r] + PI[(p * 128 + drow) * 16 + lrow];
                    FRst[drow][lrow] = f2bf(w * vR);
                    FIst[drow][lrow] = f2bf(w * vI);
                }
            }
        }
        __syncthreads();

        if (tid < 256) {
            const int dblk = tid >> 5;
            const int kgi  = (tid >> 4) & 1;
            const int dw   = tid & 15;
            const int ktile = kb2 >> 5;
            const int kg0 = (kb2 & 16) ? 2 : 0;
            const size_t go = ((size_t)((b * 8 + dblk) * NKTILE) + ktile) * 1024
                            + (kg0 + kgi) * 128 + dw * 8;
            const int d = dblk * 16 + dw;
            if (kb2 + 15 < NS) {
                *(u16x8*)&wsb[FR_OFF + go] = *(u16x8*)&FRst[d][kgi * 8];
                *(u16x8*)&wsb[FI_OFF + go] = *(u16x8*)&FIst[d][kgi * 8];
            } else {
                u16x8 fr, fi;
#pragma unroll
                for (int e = 0; e < 8; ++e) {
                    const int kc = kb2 + kgi * 8 + e;
                    fr[e] = (kc < NS) ? FRst[d][kgi * 8 + e] : (unsigned short)0;
                    fi[e] = (kc < NS) ? FIst[d][kgi * 8 + e] : (unsigned short)0;
                }
                *(u16x8*)&wsb[FR_OFF + go] = fr;
                *(u16x8*)&wsb[FI_OFF + go] = fi;
            }
        }
    }
}

// ---------------- K3: inverse DFT (32-wide ttile x split-k, 512 thr) -------------
__global__ __launch_bounds__(512) void k_inv(const int* __restrict__ len_x,
                                             const float* __restrict__ wsf,
                                             const unsigned short* __restrict__ wsb,
                                             float* __restrict__ out) {
    const int bid = blockIdx.x;
    const int b7 = bid & 7;
    const int q  = bid >> 3;
    const int b  = (q / 17) * 8 + b7;
    const int tbase = (q % 17) * 32;

    const int l = len_x[b];
    const int NS = (l >> 1) + 1;
    if (tbase >= NS) return;
    const float invl = 1.f / (float)l;
    const float fl = (float)l;

    __shared__ __align__(16) unsigned short E2c[2][16][EPAD];
    __shared__ __align__(16) unsigned short E2s[2][16][EPAD];

    const int tid = threadIdx.x;
    const int lane = tid & 63;
    const int wave8 = tid >> 6;
    const int shalf = wave8 >> 2;
    const int w4    = wave8 & 3;
    const int lrow = lane & 15, lkg = lane >> 4;

    // E-gen via per-thread recurrence: seed at k=colbase, step e^{+2pi i t/l}
    {
        const int pp = tid >> 8;
        const int t2 = tid & 255;
        const int row = t2 >> 4;
        const int colbase = (t2 & 15) * 36;
        const int tt = tbase + pp * 16 + row;   // tt < l (active blocks)
        const float tk = (float)(tt * colbase);
        float idxf = fmaf(-fl, floorf(tk * invl), tk);
        idxf = (idxf < 0.f) ? idxf + fl : idxf;
        const float rev0 = idxf * invl;
        float cr = hw_cos(rev0);
        float ci = hw_sin(rev0);                  // e^{+i th t k0}
        const float revs = (float)tt * invl;      // in [0,1)
        const float spc = hw_cos(revs);
        const float sps = hw_sin(revs);           // e^{+i th t}
#pragma unroll 6
        for (int j = 0; j < 36; j += 2) {
            unsigned cw = 0, sw = 0;
#pragma unroll
            for (int h = 0; h < 2; ++h) {
                const int kg = colbase + j + h;
                if (kg < NS) {
                    cw |= (unsigned)f2bf(cr) << (16 * h);
                    sw |= (unsigned)f2bf(ci) << (16 * h);
                }
                const float ncr = fmaf(cr, spc, -ci * sps);
                const float nci = fmaf(cr, sps, ci * spc);
                cr = ncr; ci = nci;
            }
            *(unsigned*)&E2c[pp][row][colbase + j] = cw;
            *(unsigned*)&E2s[pp][row][colbase + j] = sw;
        }
    }
    __syncthreads();

    const int dc0 = w4 * 32 + lrow;
    const int dc1 = w4 * 32 + 16 + lrow;
    const float sc0 = wsf[SCALE_OFF + b * ND + dc0];
    const float sc1 = wsf[SCALE_OFF + b * ND + dc1];
    const float bi0 = wsf[BIAS_OFF + b * ND + dc0];
    const float bi1 = wsf[BIAS_OFF + b * ND + dc1];

    f32x4 accA[2][2], accB[2][2];   // [t dblk-half][p ttile]
#pragma unroll
    for (int t = 0; t < 2; ++t)
#pragma unroll
        for (int p = 0; p < 2; ++p) { accA[t][p] = 0.f; accB[t][p] = 0.f; }

    const size_t tb0 = ((size_t)((b * 8 + 2 * w4 + 0) * NKTILE)) * 1024 + lane * 8;
    const size_t tb1 = ((size_t)((b * 8 + 2 * w4 + 1) * NKTILE)) * 1024 + lane * 8;

    const int ntile = (NS + 31) >> 5;
    const int mid = ntile >> 1;
    const int kt0 = shalf ? mid : 0;
    const int kt1 = shalf ? ntile : mid;

#pragma unroll 2
    for (int ktile = kt0; ktile < kt1; ++ktile) {
        const int k0 = ktile * 32;
        const u32x4 aC0 = *(const u32x4*)&E2c[0][lrow][k0 + lkg * 8];
        const u32x4 aS0 = *(const u32x4*)&E2s[0][lrow][k0 + lkg * 8];
        const u32x4 aC1 = *(const u32x4*)&E2c[1][lrow][k0 + lkg * 8];
        const u32x4 aS1 = *(const u32x4*)&E2s[1][lrow][k0 + lkg * 8];
        const u32x4 bR0 = *(const u32x4*)&wsb[FR_OFF + tb0 + (size_t)ktile * 1024];
        const u32x4 bI0 = *(const u32x4*)&wsb[FI_OFF + tb0 + (size_t)ktile * 1024];
        const u32x4 bR1 = *(const u32x4*)&wsb[FR_OFF + tb1 + (size_t)ktile * 1024];
        const u32x4 bI1 = *(const u32x4*)&wsb[FI_OFF + tb1 + (size_t)ktile * 1024];
        mfma16(accA[0][0], aC0, bR0);
        mfma16(accB[0][0], aS0, bI0);
        mfma16(accA[1][0], aC0, bR1);
        mfma16(accB[1][0], aS0, bI1);
        mfma16(accA[0][1], aC1, bR0);
        mfma16(accB[0][1], aS1, bI0);
        mfma16(accA[1][1], aC1, bR1);
        mfma16(accB[1][1], aS1, bI1);
    }

    // partial exchange: PA/PB f32 [2 p][128 dcol][16 ro], at +8192 inside E2c/E2s
    float* PA = (float*)((char*)&E2c[0][0][0] + 8192);
    float* PB = (float*)((char*)&E2s[0][0][0] + 8192);

    __syncthreads();
    if (shalf == 1) {
#pragma unroll
        for (int t = 0; t < 2; ++t)
#pragma unroll
            for (int p = 0; p < 2; ++p)
#pragma unroll
                for (int r = 0; r < 4; ++r) {
                    const int dcol = w4 * 32 + t * 16 + lrow;
                    PA[(p * 128 + dcol) * 16 + lkg * 4 + r] = accA[t][p][r];
                    PB[(p * 128 + dcol) * 16 + lkg * 4 + r] = accB[t][p][r];
                }
    }
    __syncthreads();

    // staging + write, per ttile p (R16 epilogue verbatim with tb2)
    float (*O1)[ND] = (float(*)[ND])&E2c[0][0][0];
    float (*O2)[ND] = (float(*)[ND])&E2s[0][0][0];

#pragma unroll
    for (int p = 0; p < 2; ++p) {
        const int tb2 = tbase + p * 16;
        if (p) __syncthreads();
        if (shalf == 0) {
#pragma unroll
            for (int t = 0; t < 2; ++t) {
                const int dcol = (t == 0) ? dc0 : dc1;
                const float sc = (t == 0) ? sc0 : sc1;
                const float bi = (t == 0) ? bi0 : bi1;
#pragma unroll
                for (int r = 0; r < 4; ++r) {
                    const int ro = lkg * 4 + r;
                    const float vA = accA[t][p][r] + PA[(p * 128 + dcol) * 16 + ro];
                    const float vB = accB[t][p][r] + PB[(p * 128 + dcol) * 16 + ro];
                    float va = (vA - vB) * sc;
                    if (tb2 + ro == 0) va += bi;
                    O1[ro][dcol] = va;
                    O2[ro][dcol] = (vA + vB) * sc;
                }
            }
        }
        __syncthreads();

        if (tid < 256) {
            const int r8 = tid >> 4;
            const int c8 = (tid & 15) * 8;
            const int trow = tb2 + r8;
            if (trow < NS) {
                float* pp = &out[((size_t)b * SL + trow) * ND + c8];
                *(float4*)pp = *(float4*)&O1[r8][c8];
                *(float4*)(pp + 4) = *(float4*)&O1[r8][c8 + 4];
                if (trow > 0 && 2 * trow != l) {
                    float* q2 = &out[((size_t)b * SL + (l - trow)) * ND + c8];
                    *(float4*)q2 = *(float4*)&O2[r8][c8];
                    *(float4*)(q2 + 4) = *(float4*)&O2[r8][c8 + 4];
                }
            }
        }
    }
}

extern "C" void kernel_launch(void* const* d_in, const int* in_sizes, int n_in,
                              void* d_out, int out_size, void* d_ws, size_t ws_size,
                              hipStream_t stream) {
    const float* x = (const float*)d_in[0];
    const float* y = (const float*)d_in[1];
    const float* z = (const float*)d_in[2];
    const int* len_x = (const int*)d_in[3];
    const int* len_y = (const int*)d_in[4];
    const int* len_z = (const int*)d_in[5];
    float* wsf = (float*)d_ws;
    unsigned short* wsb = (unsigned short*)d_ws;
    float* out = (float*)d_out;

    k_front<<<928, 256, 0, stream>>>(x, y, z, len_x, wsf, wsb, out);

    k_fwd_mlp<<<304, 512, 0, stream>>>(len_x, len_y, len_z, wsf, wsb,
        (const float*)d_in[6],  (const float*)d_in[7],  (const float*)d_in[8],  (const float*)d_in[9],
        (const float*)d_in[10], (const float*)d_in[11], (const float*)d_in[12], (const float*)d_in[13],
        (const float*)d_in[14], (const float*)d_in[15], (const float*)d_in[16], (const float*)d_in[17],
        (const float*)d_in[18], (const float*)d_in[19], (const float*)d_in[20], (const float*)d_in[21]);

    k_inv<<<272, 512, 0, stream>>>(len_x, wsf, wsb, out);
}